// Round 4
// baseline (25.163 us; speedup 1.0000x reference)
//
#include <hip/hip_runtime.h>

// Problem constants (match reference)
static constexpr int CB = 2;
static constexpr int CN = 256;
static constexpr int CK = 16;
#define F_ALPHA 0.01f
#define F_LAM   1.0f
#define F_KAPPA 1.0f
#define F_EPS   1e-6f
#define F_GCLIP 1000.0f

// ---------------------------------------------------------------------------
// Kernel 1: per (b,n):
//   R = expm(sum_a phi_a G_a)  (orthogonal; scale 1/16 + 8-term Taylor + 4 sq)
//   u = R^T mu_q               -> wsUT[b][c][n]           (coalesced for K2)
//   W = R^T diag(1/(sig+eps)) R -> wsWT4[b][g][n][4]      (g=k/4, float4/lane)
//   R -> wsR[b][n][16][16] row-major (epilogue-only use)
// W/R stores go through LDS and out as float4 chunks (coalesced-ish).
// ---------------------------------------------------------------------------
__global__ __launch_bounds__(256) void vfe_prep_kernel(
    const float* __restrict__ mu_q, const float* __restrict__ sigma_q,
    const float* __restrict__ phi, const float* __restrict__ gens,
    float* __restrict__ wsR, float* __restrict__ wsWT4, float* __restrict__ wsUT)
{
    const int bn = blockIdx.x;          // 0 .. B*N-1
    const int b  = bn >> 8;
    const int n  = bn & 255;
    const int t  = threadIdx.x;         // element (r,c)
    const int r  = t >> 4;
    const int c  = t & 15;

    __shared__ float Ms[256];
    __shared__ float Pa[256], Pb[256];
    __shared__ float Ta[256], Tb[256];
    __shared__ float Wst[256];
    __shared__ float msh[CK], dinv[CK];

    const float p0 = phi[bn*3+0];
    const float p1 = phi[bn*3+1];
    const float p2 = phi[bn*3+2];

    const float diag = (r == c) ? 1.0f : 0.0f;
    float m = p0*gens[t] + p1*gens[256+t] + p2*gens[512+t];
    m *= (1.0f/16.0f);                  // 4 squarings later
    Ms[t] = m;
    Pa[t] = m;
    if (t < CK) {
        msh[t]  = mu_q[bn*CK + t];
        dinv[t] = 1.0f / (fmaxf(sigma_q[bn*CK + t], F_EPS) + F_EPS);
    }
    __syncthreads();

    // cache column c of Ms in registers
    float mscol[CK];
    #pragma unroll
    for (int l = 0; l < CK; ++l) mscol[l] = Ms[l*CK + c];

    float Treg = diag + m;
    // Taylor k=2..8, ping-pong Pa/Pb, 1 barrier/iter
    #pragma unroll
    for (int k = 2; k <= 8; ++k) {
        const float* Pc = (k & 1) ? Pb : Pa;
        float*       Pn = (k & 1) ? Pa : Pb;
        float acc = 0.f;
        #pragma unroll
        for (int l = 0; l < CK; ++l) acc += Pc[r*CK+l] * mscol[l];
        acc *= (1.0f / (float)k);
        Pn[t] = acc;
        Treg += acc;
        __syncthreads();
    }

    // 4 squarings, ping-pong Ta/Tb; final lands in Ta
    Ta[t] = Treg;
    __syncthreads();
    #pragma unroll
    for (int s = 0; s < 4; ++s) {
        const float* Tc = (s & 1) ? Tb : Ta;
        float*       Tn = (s & 1) ? Ta : Tb;
        float acc = 0.f;
        #pragma unroll
        for (int l = 0; l < CK; ++l) acc += Tc[r*CK+l] * Tc[l*CK+c];
        Tn[t] = acc;
        __syncthreads();
    }
    // Ta = R (all lanes synced)

    // u = R^T mu (threads 0..15), scattered singles (tiny)
    if (t < CK) {
        float acc = 0.f;
        #pragma unroll
        for (int l = 0; l < CK; ++l) acc += Ta[l*CK+t] * msh[l];
        wsUT[(b*CK + t)*CN + n] = acc;
    }

    // R store: threads 64..127 write float4 chunks from Ta
    if (t >= 64 && t < 128) {
        const int g = t - 64;
        float4 v;
        v.x = Ta[4*g+0]; v.y = Ta[4*g+1]; v.z = Ta[4*g+2]; v.w = Ta[4*g+3];
        ((float4*)wsR)[bn*64 + g] = v;
    }

    // W element (r,c) -> Wst
    {
        float acc = 0.f;
        #pragma unroll
        for (int l = 0; l < CK; ++l) acc += Ta[l*CK+r] * dinv[l] * Ta[l*CK+c];
        Wst[t] = acc;
    }
    __syncthreads();

    // W store: threads 0..63 write float4 chunk g at [b][g][n]
    if (t < 64) {
        float4 v;
        v.x = Wst[4*t+0]; v.y = Wst[4*t+1]; v.z = Wst[4*t+2]; v.w = Wst[4*t+3];
        ((float4*)wsWT4)[(b*64 + t)*256 + n] = v;
    }
}

// ---------------------------------------------------------------------------
// Kernel 2: 256 blocks; block handles TWO rows i0,i0+1 of batch b (W reuse x2).
// Thread j: d = u_i - u_j ; h = W_j d ; kl = 0.5 d.h ; accumulate
//   s1=Σβh, s2=Σβ·kl·h, s3=Σβ·kl  ->  grad = R_i (LAM s1 + LAM/κ (s2 - s3 s1))
// W loads: 64 dwordx4/thread, lane-coalesced over j.
// Reduction: 3-step butterfly (64->8 lanes) + LDS transpose finish.
// ---------------------------------------------------------------------------
__global__ __launch_bounds__(256) void vfe_pair_kernel(
    const float* __restrict__ mu_q, const float* __restrict__ sigma_q,
    const float* __restrict__ mu_p, const float* __restrict__ sigma_p,
    const float* __restrict__ beta, const float* __restrict__ lr,
    const float* __restrict__ wsR, const float* __restrict__ wsWT4,
    const float* __restrict__ wsUT, float* __restrict__ out)
{
    const int bid = blockIdx.x;     // 0..255
    const int b   = bid >> 7;
    const int i0  = (bid & 127) * 2;
    const int j   = threadIdx.x;    // 0..255
    const int lane = j & 63;
    const int wv   = j >> 6;

    __shared__ float uish[2][CK];
    __shared__ float part[32][67];  // [wv*8+l][q], pad 67 -> conflict-free
    __shared__ float red[66];
    __shared__ float grot[2][CK];

    if (j < 32) uish[j >> 4][j & 15] = wsUT[(b*CK + (j & 15))*CN + i0 + (j >> 4)];
    __syncthreads();

    // d = u_i - u_j (coalesced b32)
    const float* uTb = wsUT + b*CK*CN;
    float d1[CK], d2[CK];
    #pragma unroll
    for (int cc = 0; cc < CK; ++cc) {
        const float uj = uTb[cc*CN + j];
        d1[cc] = uish[0][cc] - uj;
        d2[cc] = uish[1][cc] - uj;
    }

    // h = W_j d for both i's; 64 dwordx4 loads
    const float4* W4 = ((const float4*)wsWT4) + b*64*256 + j;
    float h1[CK], h2[CK];
    float kl1 = 0.f, kl2 = 0.f;
    #pragma unroll
    for (int rr = 0; rr < CK; ++rr) {
        float a1 = 0.f, a2 = 0.f;
        #pragma unroll
        for (int c4 = 0; c4 < 4; ++c4) {
            const float4 w = W4[(rr*4 + c4)*256];
            a1 += w.x*d1[4*c4+0] + w.y*d1[4*c4+1] + w.z*d1[4*c4+2] + w.w*d1[4*c4+3];
            a2 += w.x*d2[4*c4+0] + w.y*d2[4*c4+1] + w.z*d2[4*c4+2] + w.w*d2[4*c4+3];
        }
        h1[rr] = a1; kl1 += a1*d1[rr];
        h2[rr] = a2; kl2 += a2*d2[rr];
    }
    kl1 *= 0.5f; kl2 *= 0.5f;

    const float bt1  = beta[(b*CN + i0    )*CN + j];
    const float bt2  = beta[(b*CN + i0 + 1)*CN + j];
    const float wkl1 = bt1*kl1;
    const float wkl2 = bt2*kl2;

    // 66 accumulands; butterfly 64->8 lanes then LDS
    #pragma unroll
    for (int q = 0; q < 66; ++q) {
        const int il = (q < 33) ? 0 : 1;
        const int qq = (q < 33) ? q : q - 33;
        float x;
        if (il == 0) x = (qq < 16) ? bt1*h1[qq] : (qq < 32 ? wkl1*h1[qq-16] : wkl1);
        else         x = (qq < 16) ? bt2*h2[qq] : (qq < 32 ? wkl2*h2[qq-16] : wkl2);
        x += __shfl_down(x, 32);
        x += __shfl_down(x, 16);
        x += __shfl_down(x, 8);
        if (lane < 8) part[wv*8 + lane][q] = x;
    }
    __syncthreads();

    if (j < 66) {
        float s = 0.f;
        #pragma unroll
        for (int mm = 0; mm < 32; ++mm) s += part[mm][j];
        red[j] = s;
    }
    __syncthreads();

    if (j < 32) {
        const int il = j >> 4, rr = j & 15, q0 = il*33;
        const float s1 = red[q0 + rr];
        const float s2 = red[q0 + 16 + rr];
        const float s3 = red[q0 + 32];
        grot[il][rr] = F_LAM*s1 + (F_LAM/F_KAPPA)*(s2 - s3*s1);
    }
    __syncthreads();

    if (j < 32) {
        const int il = j >> 4, rr = j & 15;
        const int i  = i0 + il;
        const float* Ri = wsR + (b*CN + i)*256 + rr*CK;
        float acc = 0.f;
        #pragma unroll
        for (int cc = 0; cc < CK; ++cc) acc += Ri[cc] * grot[il][cc];

        const int idx = (b*CN + i)*CK + rr;
        const float mq = mu_q[idx];
        const float sq = sigma_q[idx];
        const float mp = mu_p[idx];
        const float sp = sigma_p[idx];
        const float sps = fmaxf(sp, F_EPS);
        const float sqs = fmaxf(sq, F_EPS);

        const float gmu = F_ALPHA*(mq - mp)/sps + acc;
        const float gsg = F_ALPHA*0.5f*(1.0f/sps - 1.0f/sqs);

        float nmu = sqs * gmu;
        float nsg = 0.5f * sqs * sqs * gsg;
        nmu = fminf(fmaxf(nmu, -F_GCLIP), F_GCLIP);
        nsg = fminf(fmaxf(nsg, -F_GCLIP), F_GCLIP);

        const float step = lr[0];
        out[idx]             = mq - step*nmu;                 // mu_new
        out[CB*CN*CK + idx]  = fmaxf(sq - step*nsg, F_EPS);   // sigma_new
    }
}

extern "C" void kernel_launch(void* const* d_in, const int* in_sizes, int n_in,
                              void* d_out, int out_size, void* d_ws, size_t ws_size,
                              hipStream_t stream) {
    const float* mu_q    = (const float*)d_in[0];
    const float* sigma_q = (const float*)d_in[1];
    const float* mu_p    = (const float*)d_in[2];
    const float* sigma_p = (const float*)d_in[3];
    const float* beta    = (const float*)d_in[4];
    const float* phi     = (const float*)d_in[5];
    const float* gens    = (const float*)d_in[6];
    const float* lr      = (const float*)d_in[7];
    float* out = (float*)d_out;

    float* wsR   = (float*)d_ws;               // [b][n][16][16]
    float* wsWT4 = wsR + CB*CN*CK*CK;          // [b][g][n][4]
    float* wsUT  = wsWT4 + CB*CN*CK*CK;        // [b][c][n]

    vfe_prep_kernel<<<CB*CN, 256, 0, stream>>>(mu_q, sigma_q, phi, gens, wsR, wsWT4, wsUT);
    vfe_pair_kernel<<<CB*CN/2, 256, 0, stream>>>(mu_q, sigma_q, mu_p, sigma_p, beta, lr,
                                                 wsR, wsWT4, wsUT, out);
}

// Round 5
// 21.401 us; speedup vs baseline: 1.1758x; 1.1758x over previous
//
#include <hip/hip_runtime.h>

// Problem constants (match reference)
static constexpr int CB = 2;
static constexpr int CN = 256;
static constexpr int CK = 16;
#define F_ALPHA 0.01f
#define F_LAM   1.0f
#define F_KAPPA 1.0f
#define F_EPS   1e-6f
#define F_GCLIP 1000.0f

// ---------------------------------------------------------------------------
// Kernel 1: per (b,n):
//   R = expm(sum_a phi_a G_a)  (orthogonal; scale 1/16 + 8-term Taylor + 4 sq)
//   u = R^T mu_q               -> wsUT[b][c][n]           (coalesced for K2)
//   W = R^T diag(1/(sig+eps)) R -> wsWT4[b][g][n][4]      (g=k/4, float4/lane)
//   R -> wsR[b][n][16][16] row-major (epilogue-only use)
// ---------------------------------------------------------------------------
__global__ __launch_bounds__(256) void vfe_prep_kernel(
    const float* __restrict__ mu_q, const float* __restrict__ sigma_q,
    const float* __restrict__ phi, const float* __restrict__ gens,
    float* __restrict__ wsR, float* __restrict__ wsWT4, float* __restrict__ wsUT)
{
    const int bn = blockIdx.x;          // 0 .. B*N-1
    const int b  = bn >> 8;
    const int n  = bn & 255;
    const int t  = threadIdx.x;         // element (r,c)
    const int r  = t >> 4;
    const int c  = t & 15;

    __shared__ float Ms[256];
    __shared__ float Pa[256], Pb[256];
    __shared__ float Ta[256], Tb[256];
    __shared__ float Wst[256];
    __shared__ float msh[CK], dinv[CK];

    const float p0 = phi[bn*3+0];
    const float p1 = phi[bn*3+1];
    const float p2 = phi[bn*3+2];

    const float diag = (r == c) ? 1.0f : 0.0f;
    float m = p0*gens[t] + p1*gens[256+t] + p2*gens[512+t];
    m *= (1.0f/16.0f);                  // 4 squarings later
    Ms[t] = m;
    Pa[t] = m;
    if (t < CK) {
        msh[t]  = mu_q[bn*CK + t];
        dinv[t] = 1.0f / (fmaxf(sigma_q[bn*CK + t], F_EPS) + F_EPS);
    }
    __syncthreads();

    // cache column c of Ms in registers
    float mscol[CK];
    #pragma unroll
    for (int l = 0; l < CK; ++l) mscol[l] = Ms[l*CK + c];

    float Treg = diag + m;
    // Taylor k=2..8, ping-pong Pa/Pb, 1 barrier/iter
    #pragma unroll
    for (int k = 2; k <= 8; ++k) {
        const float* Pc = (k & 1) ? Pb : Pa;
        float*       Pn = (k & 1) ? Pa : Pb;
        float acc = 0.f;
        #pragma unroll
        for (int l = 0; l < CK; ++l) acc += Pc[r*CK+l] * mscol[l];
        acc *= (1.0f / (float)k);
        Pn[t] = acc;
        Treg += acc;
        __syncthreads();
    }

    // 4 squarings, ping-pong Ta/Tb; final lands in Ta
    Ta[t] = Treg;
    __syncthreads();
    #pragma unroll
    for (int s = 0; s < 4; ++s) {
        const float* Tc = (s & 1) ? Tb : Ta;
        float*       Tn = (s & 1) ? Ta : Tb;
        float acc = 0.f;
        #pragma unroll
        for (int l = 0; l < CK; ++l) acc += Tc[r*CK+l] * Tc[l*CK+c];
        Tn[t] = acc;
        __syncthreads();
    }
    // Ta = R (all lanes synced)

    // u = R^T mu (threads 0..15)
    if (t < CK) {
        float acc = 0.f;
        #pragma unroll
        for (int l = 0; l < CK; ++l) acc += Ta[l*CK+t] * msh[l];
        wsUT[(b*CK + t)*CN + n] = acc;
    }

    // R store: threads 64..127 write float4 chunks from Ta
    if (t >= 64 && t < 128) {
        const int g = t - 64;
        float4 v;
        v.x = Ta[4*g+0]; v.y = Ta[4*g+1]; v.z = Ta[4*g+2]; v.w = Ta[4*g+3];
        ((float4*)wsR)[bn*64 + g] = v;
    }

    // W element (r,c) -> Wst
    {
        float acc = 0.f;
        #pragma unroll
        for (int l = 0; l < CK; ++l) acc += Ta[l*CK+r] * dinv[l] * Ta[l*CK+c];
        Wst[t] = acc;
    }
    __syncthreads();

    // W store: threads 0..63 write float4 chunk g at [b][g][n]
    if (t < 64) {
        float4 v;
        v.x = Wst[4*t+0]; v.y = Wst[4*t+1]; v.z = Wst[4*t+2]; v.w = Wst[4*t+3];
        ((float4*)wsWT4)[(b*64 + t)*256 + n] = v;
    }
}

// ---------------------------------------------------------------------------
// Kernel 2 (R3 structure, float4 W reads): one block per (b,i), thread per j.
//   d = u_i - u_j ; h = W_j d ; kl = 0.5 d.h
//   s1=Σβh ; s2=Σβ·kl·h ; s3=Σβ·kl ; grad = R_i (LAM·s1 + LAM/κ·(s2 - s3·s1))
// W loads: 64 dwordx4/thread, lane-coalesced over j (stride 4KB rows).
// ---------------------------------------------------------------------------
__global__ __launch_bounds__(256) void vfe_pair_kernel(
    const float* __restrict__ mu_q, const float* __restrict__ sigma_q,
    const float* __restrict__ mu_p, const float* __restrict__ sigma_p,
    const float* __restrict__ beta, const float* __restrict__ lr,
    const float* __restrict__ wsR, const float* __restrict__ wsWT4,
    const float* __restrict__ wsUT, float* __restrict__ out)
{
    const int bi = blockIdx.x;      // b*N + i
    const int b  = bi >> 8;
    const int i  = bi & 255;
    const int j  = threadIdx.x;     // 0..255

    __shared__ float uish[CK];
    __shared__ float part[4][33];
    __shared__ float red[33];
    __shared__ float grot[CK];

    if (j < CK) uish[j] = wsUT[(b*CK + j)*CN + i];
    __syncthreads();

    // d = u_i - u_j   (coalesced b32 reads)
    const float* uTb = wsUT + b*CK*CN;
    float d[CK];
    #pragma unroll
    for (int cc = 0; cc < CK; ++cc) d[cc] = uish[cc] - uTb[cc*CN + j];

    // h = W_j d ; kl = 0.5 d.h   (64 lane-coalesced dwordx4)
    const float4* W4 = ((const float4*)wsWT4) + b*64*256 + j;
    float h[CK];
    float kl = 0.f;
    #pragma unroll
    for (int rr = 0; rr < CK; ++rr) {
        float acc = 0.f;
        #pragma unroll
        for (int c4 = 0; c4 < 4; ++c4) {
            const float4 w = W4[(rr*4 + c4)*256];
            acc += w.x*d[4*c4+0] + w.y*d[4*c4+1] + w.z*d[4*c4+2] + w.w*d[4*c4+3];
        }
        h[rr] = acc;
        kl += acc * d[rr];
    }
    kl *= 0.5f;

    const float bt  = beta[(b*CN + i)*CN + j];
    const float wkl = bt * kl;

    // 33 accumulands: [0..15]=bt*h, [16..31]=wkl*h, [32]=wkl
    float v[33];
    #pragma unroll
    for (int q = 0; q < CK; ++q) { v[q] = bt*h[q]; v[16+q] = wkl*h[q]; }
    v[32] = wkl;

    // wave64 butterfly then cross-wave via LDS
    #pragma unroll
    for (int q = 0; q < 33; ++q) {
        float x = v[q];
        x += __shfl_down(x, 32);
        x += __shfl_down(x, 16);
        x += __shfl_down(x, 8);
        x += __shfl_down(x, 4);
        x += __shfl_down(x, 2);
        x += __shfl_down(x, 1);
        v[q] = x;
    }
    const int lane = j & 63;
    const int wv   = j >> 6;
    if (lane == 0) {
        #pragma unroll
        for (int q = 0; q < 33; ++q) part[wv][q] = v[q];
    }
    __syncthreads();
    if (j < 33) red[j] = part[0][j] + part[1][j] + part[2][j] + part[3][j];
    __syncthreads();

    if (j < CK) {
        const float s1 = red[j];
        const float s2 = red[16+j];
        const float s3 = red[32];
        grot[j] = F_LAM*s1 + (F_LAM/F_KAPPA)*(s2 - s3*s1);
    }
    __syncthreads();

    if (j < CK) {
        const int rr = j;
        const float* Ri = wsR + bi*256;
        float acc = 0.f;
        #pragma unroll
        for (int cc = 0; cc < CK; ++cc) acc += Ri[rr*CK+cc] * grot[cc];

        const int idx = bi*CK + rr;
        const float mq = mu_q[idx];
        const float sq = sigma_q[idx];
        const float mp = mu_p[idx];
        const float sp = sigma_p[idx];
        const float sps = fmaxf(sp, F_EPS);
        const float sqs = fmaxf(sq, F_EPS);

        const float gmu = F_ALPHA*(mq - mp)/sps + acc;
        const float gsg = F_ALPHA*0.5f*(1.0f/sps - 1.0f/sqs);

        float nmu = sqs * gmu;
        float nsg = 0.5f * sqs * sqs * gsg;
        nmu = fminf(fmaxf(nmu, -F_GCLIP), F_GCLIP);
        nsg = fminf(fmaxf(nsg, -F_GCLIP), F_GCLIP);

        const float step = lr[0];
        out[idx]             = mq - step*nmu;                 // mu_new
        out[CB*CN*CK + idx]  = fmaxf(sq - step*nsg, F_EPS);   // sigma_new
    }
}

extern "C" void kernel_launch(void* const* d_in, const int* in_sizes, int n_in,
                              void* d_out, int out_size, void* d_ws, size_t ws_size,
                              hipStream_t stream) {
    const float* mu_q    = (const float*)d_in[0];
    const float* sigma_q = (const float*)d_in[1];
    const float* mu_p    = (const float*)d_in[2];
    const float* sigma_p = (const float*)d_in[3];
    const float* beta    = (const float*)d_in[4];
    const float* phi     = (const float*)d_in[5];
    const float* gens    = (const float*)d_in[6];
    const float* lr      = (const float*)d_in[7];
    float* out = (float*)d_out;

    float* wsR   = (float*)d_ws;               // [b][n][16][16]
    float* wsWT4 = wsR + CB*CN*CK*CK;          // [b][g][n][4]
    float* wsUT  = wsWT4 + CB*CN*CK*CK;        // [b][c][n]

    vfe_prep_kernel<<<CB*CN, 256, 0, stream>>>(mu_q, sigma_q, phi, gens, wsR, wsWT4, wsUT);
    vfe_pair_kernel<<<CB*CN, 256, 0, stream>>>(mu_q, sigma_q, mu_p, sigma_p, beta, lr,
                                               wsR, wsWT4, wsUT, out);
}

// Round 6
// 20.059 us; speedup vs baseline: 1.2545x; 1.0669x over previous
//
#include <hip/hip_runtime.h>

// Problem constants (match reference)
static constexpr int CB = 2;
static constexpr int CN = 256;
static constexpr int CK = 16;
#define F_ALPHA 0.01f
#define F_LAM   1.0f
#define F_KAPPA 1.0f
#define F_EPS   1e-6f
#define F_GCLIP 1000.0f

// ---------------------------------------------------------------------------
// Kernel 1 (unchanged from R5): per (b,n):
//   R = expm(sum_a phi_a G_a)  (orthogonal; scale 1/16 + 8-term Taylor + 4 sq)
//   u = R^T mu_q               -> wsUT[b][c][n]
//   W = R^T diag(1/(sig+eps)) R -> wsWT4[b][g][n][4]
//   R -> wsR[b][n][16][16]
// ---------------------------------------------------------------------------
__global__ __launch_bounds__(256) void vfe_prep_kernel(
    const float* __restrict__ mu_q, const float* __restrict__ sigma_q,
    const float* __restrict__ phi, const float* __restrict__ gens,
    float* __restrict__ wsR, float* __restrict__ wsWT4, float* __restrict__ wsUT)
{
    const int bn = blockIdx.x;          // 0 .. B*N-1
    const int b  = bn >> 8;
    const int n  = bn & 255;
    const int t  = threadIdx.x;         // element (r,c)
    const int r  = t >> 4;
    const int c  = t & 15;

    __shared__ float Ms[256];
    __shared__ float Pa[256], Pb[256];
    __shared__ float Ta[256], Tb[256];
    __shared__ float Wst[256];
    __shared__ float msh[CK], dinv[CK];

    const float p0 = phi[bn*3+0];
    const float p1 = phi[bn*3+1];
    const float p2 = phi[bn*3+2];

    const float diag = (r == c) ? 1.0f : 0.0f;
    float m = p0*gens[t] + p1*gens[256+t] + p2*gens[512+t];
    m *= (1.0f/16.0f);                  // 4 squarings later
    Ms[t] = m;
    Pa[t] = m;
    if (t < CK) {
        msh[t]  = mu_q[bn*CK + t];
        dinv[t] = 1.0f / (fmaxf(sigma_q[bn*CK + t], F_EPS) + F_EPS);
    }
    __syncthreads();

    // cache column c of Ms in registers
    float mscol[CK];
    #pragma unroll
    for (int l = 0; l < CK; ++l) mscol[l] = Ms[l*CK + c];

    float Treg = diag + m;
    // Taylor k=2..8, ping-pong Pa/Pb, 1 barrier/iter
    #pragma unroll
    for (int k = 2; k <= 8; ++k) {
        const float* Pc = (k & 1) ? Pb : Pa;
        float*       Pn = (k & 1) ? Pa : Pb;
        float acc = 0.f;
        #pragma unroll
        for (int l = 0; l < CK; ++l) acc += Pc[r*CK+l] * mscol[l];
        acc *= (1.0f / (float)k);
        Pn[t] = acc;
        Treg += acc;
        __syncthreads();
    }

    // 4 squarings, ping-pong Ta/Tb; final lands in Ta
    Ta[t] = Treg;
    __syncthreads();
    #pragma unroll
    for (int s = 0; s < 4; ++s) {
        const float* Tc = (s & 1) ? Tb : Ta;
        float*       Tn = (s & 1) ? Ta : Tb;
        float acc = 0.f;
        #pragma unroll
        for (int l = 0; l < CK; ++l) acc += Tc[r*CK+l] * Tc[l*CK+c];
        Tn[t] = acc;
        __syncthreads();
    }
    // Ta = R (all lanes synced)

    // u = R^T mu (threads 0..15)
    if (t < CK) {
        float acc = 0.f;
        #pragma unroll
        for (int l = 0; l < CK; ++l) acc += Ta[l*CK+t] * msh[l];
        wsUT[(b*CK + t)*CN + n] = acc;
    }

    // R store: threads 64..127 write float4 chunks from Ta
    if (t >= 64 && t < 128) {
        const int g = t - 64;
        float4 v;
        v.x = Ta[4*g+0]; v.y = Ta[4*g+1]; v.z = Ta[4*g+2]; v.w = Ta[4*g+3];
        ((float4*)wsR)[bn*64 + g] = v;
    }

    // W element (r,c) -> Wst
    {
        float acc = 0.f;
        #pragma unroll
        for (int l = 0; l < CK; ++l) acc += Ta[l*CK+r] * dinv[l] * Ta[l*CK+c];
        Wst[t] = acc;
    }
    __syncthreads();

    // W store: threads 0..63 write float4 chunk g at [b][g][n]
    if (t < 64) {
        float4 v;
        v.x = Wst[4*t+0]; v.y = Wst[4*t+1]; v.z = Wst[4*t+2]; v.w = Wst[4*t+3];
        ((float4*)wsWT4)[(b*64 + t)*256 + n] = v;
    }
}

// ---------------------------------------------------------------------------
// Kernel 2: one block per (b,i), thread per j. R5 compute phase, but the
// 33-value 6-step butterfly (198 shuffles) is replaced by an H-in-LDS
// two-phase reduction:
//   Phase A (thread=j): d = u_i - u_j; h = W_j d; kl = 0.5 d.h;
//                       H[j][k] <- h[k], bets[j] <- beta, bkls[j] <- beta*kl
//   Phase B (thread=(jg,k)): s1p = sum_{s<16} bets[jg*16+s] * H[..][k]
//                            s2p = sum        bkls[..] * H[..][k]
//                            s3p = sum        bkls[..]
//                            2-step wave shuffle over jg -> partials
//   Phase C (thread=k<16): grot = LAM*s1 + LAM/kappa*(s2 - s3*s1)
// ---------------------------------------------------------------------------
__global__ __launch_bounds__(256) void vfe_pair_kernel(
    const float* __restrict__ mu_q, const float* __restrict__ sigma_q,
    const float* __restrict__ mu_p, const float* __restrict__ sigma_p,
    const float* __restrict__ beta, const float* __restrict__ lr,
    const float* __restrict__ wsR, const float* __restrict__ wsWT4,
    const float* __restrict__ wsUT, float* __restrict__ out)
{
    const int bi = blockIdx.x;      // b*N + i
    const int b  = bi >> 8;
    const int i  = bi & 255;
    const int t  = threadIdx.x;     // 0..255 (= j in phase A)

    __shared__ float uish[CK];
    __shared__ float Hs[256][17];   // pad 17 -> conflict-free writes, 2-way reads
    __shared__ float bets[256];
    __shared__ float bkls[256];
    __shared__ float partS1[4][16];
    __shared__ float partS2[4][16];
    __shared__ float partS3[4];
    __shared__ float grot[CK];

    if (t < CK) uish[t] = wsUT[(b*CK + t)*CN + i];
    __syncthreads();

    // ---- Phase A ----
    const float* uTb = wsUT + b*CK*CN;
    float d[CK];
    #pragma unroll
    for (int cc = 0; cc < CK; ++cc) d[cc] = uish[cc] - uTb[cc*CN + t];

    const float4* W4 = ((const float4*)wsWT4) + b*64*256 + t;
    float kl = 0.f;
    #pragma unroll
    for (int rr = 0; rr < CK; ++rr) {
        float acc = 0.f;
        #pragma unroll
        for (int c4 = 0; c4 < 4; ++c4) {
            const float4 w = W4[(rr*4 + c4)*256];
            acc += w.x*d[4*c4+0] + w.y*d[4*c4+1] + w.z*d[4*c4+2] + w.w*d[4*c4+3];
        }
        Hs[t][rr] = acc;
        kl += acc * d[rr];
    }
    kl *= 0.5f;

    const float bt = beta[(b*CN + i)*CN + t];
    bets[t] = bt;
    bkls[t] = bt * kl;
    __syncthreads();

    // ---- Phase B: thread = (jg = t>>4, k = t&15) ----
    const int k  = t & 15;
    const int jg = t >> 4;
    float s1p = 0.f, s2p = 0.f, s3p = 0.f;
    #pragma unroll
    for (int s = 0; s < 16; ++s) {
        const int jj = jg*16 + s;
        const float hv = Hs[jj][k];
        const float be = bets[jj];
        const float bk = bkls[jj];
        s1p += be * hv;
        s2p += bk * hv;
        s3p += bk;
    }
    // reduce over the 4 jg's within this wave (lanes l, l+16, l+32, l+48)
    s1p += __shfl_down(s1p, 16);  s1p += __shfl_down(s1p, 32);
    s2p += __shfl_down(s2p, 16);  s2p += __shfl_down(s2p, 32);
    s3p += __shfl_down(s3p, 16);  s3p += __shfl_down(s3p, 32);

    const int lane = t & 63;
    const int wv   = t >> 6;
    if (lane < 16) {
        partS1[wv][lane] = s1p;
        partS2[wv][lane] = s2p;
        if (lane == 0) partS3[wv] = s3p;
    }
    __syncthreads();

    // ---- Phase C ----
    if (t < CK) {
        const float s1 = partS1[0][t] + partS1[1][t] + partS1[2][t] + partS1[3][t];
        const float s2 = partS2[0][t] + partS2[1][t] + partS2[2][t] + partS2[3][t];
        const float s3 = partS3[0] + partS3[1] + partS3[2] + partS3[3];
        grot[t] = F_LAM*s1 + (F_LAM/F_KAPPA)*(s2 - s3*s1);
    }
    __syncthreads();

    // ---- Epilogue ----
    if (t < CK) {
        const int rr = t;
        const float* Ri = wsR + bi*256;
        float acc = 0.f;
        #pragma unroll
        for (int cc = 0; cc < CK; ++cc) acc += Ri[rr*CK+cc] * grot[cc];

        const int idx = bi*CK + rr;
        const float mq = mu_q[idx];
        const float sq = sigma_q[idx];
        const float mp = mu_p[idx];
        const float sp = sigma_p[idx];
        const float sps = fmaxf(sp, F_EPS);
        const float sqs = fmaxf(sq, F_EPS);

        const float gmu = F_ALPHA*(mq - mp)/sps + acc;
        const float gsg = F_ALPHA*0.5f*(1.0f/sps - 1.0f/sqs);

        float nmu = sqs * gmu;
        float nsg = 0.5f * sqs * sqs * gsg;
        nmu = fminf(fmaxf(nmu, -F_GCLIP), F_GCLIP);
        nsg = fminf(fmaxf(nsg, -F_GCLIP), F_GCLIP);

        const float step = lr[0];
        out[idx]             = mq - step*nmu;                 // mu_new
        out[CB*CN*CK + idx]  = fmaxf(sq - step*nsg, F_EPS);   // sigma_new
    }
}

extern "C" void kernel_launch(void* const* d_in, const int* in_sizes, int n_in,
                              void* d_out, int out_size, void* d_ws, size_t ws_size,
                              hipStream_t stream) {
    const float* mu_q    = (const float*)d_in[0];
    const float* sigma_q = (const float*)d_in[1];
    const float* mu_p    = (const float*)d_in[2];
    const float* sigma_p = (const float*)d_in[3];
    const float* beta    = (const float*)d_in[4];
    const float* phi     = (const float*)d_in[5];
    const float* gens    = (const float*)d_in[6];
    const float* lr      = (const float*)d_in[7];
    float* out = (float*)d_out;

    float* wsR   = (float*)d_ws;               // [b][n][16][16]
    float* wsWT4 = wsR + CB*CN*CK*CK;          // [b][g][n][4]
    float* wsUT  = wsWT4 + CB*CN*CK*CK;        // [b][c][n]

    vfe_prep_kernel<<<CB*CN, 256, 0, stream>>>(mu_q, sigma_q, phi, gens, wsR, wsWT4, wsUT);
    vfe_pair_kernel<<<CB*CN, 256, 0, stream>>>(mu_q, sigma_q, mu_p, sigma_p, beta, lr,
                                               wsR, wsWT4, wsUT, out);
}